// Round 5
// baseline (651.361 us; speedup 1.0000x reference)
//
#include <hip/hip_runtime.h>
#include <hip/hip_bf16.h>

constexpr int kC  = 20;              // NUM_CLASSES
constexpr int kP  = 8192;            // NUM_PARCELS
constexpr int kIgnore = 255;         // IGNORE_INDEX
constexpr int kHW = 512 * 512;       // 2^18
constexpr int kM  = 8 * kHW;         // 2097152 pixels

constexpr int NB1 = 256;             // kA chunks
constexpr int CH1 = kM / NB1;        // 8192

constexpr int NG  = 5;               // class groups
constexpr int CPG = 4;               // classes per group
constexpr int NCH = 51;              // kC chunks per group (5*51=255 blocks = ~1/CU)
constexpr int CH2 = (kM + NCH - 1) / NCH;   // 41122 (even)

// ---- workspace layout (bytes) ----
constexpr size_t oPv      = 0;                                    // kM*2      = 4 MB
constexpr size_t oHist    = oPv   + (size_t)kM * 2;               // NB1*kP*4  = 8 MB
constexpr size_t oMinb    = oHist + (size_t)NB1 * kP * 4;         // 8 MB
constexpr size_t oCnt     = oMinb + (size_t)NB1 * kP * 4;         // 32 KB
constexpr size_t oFirst   = oCnt  + (size_t)kP * 4;               // 32 KB
constexpr size_t oAcc     = oFirst + (size_t)kP * 4;              // 256 B
constexpr size_t oPartial = oAcc + 256;                           // 255*8192*4*4 = 33.4 MB
constexpr size_t kNeedMain = oPartial + (size_t)NG * NCH * kP * CPG * 4;  // ~54 MB

// ---- kA: pack parcel|valid to u16 + per-chunk hist/minb ----
__global__ __launch_bounds__(256)
void kA_pack(const int* __restrict__ target, const int* __restrict__ parcel,
             unsigned short* __restrict__ pv, int* __restrict__ hist,
             int* __restrict__ minb) {
    __shared__ int lh[kP];
    __shared__ int lm[kP];
    const int b = blockIdx.x;
    for (int p = threadIdx.x; p < kP; p += 256) { lh[p] = 0; lm[p] = kM; }
    __syncthreads();
    const int base = b * CH1;
    for (int j = threadIdx.x; j < CH1; j += 256) {
        const int i = base + j;
        const int t = target[i];
        const int p = parcel[i];
        const bool valid = (t != kIgnore);
        pv[i] = valid ? (unsigned short)p : (unsigned short)0xFFFF;
        if (valid) { atomicAdd(&lh[p], 1); atomicMin(&lm[p], i); }
    }
    __syncthreads();
    int* hb = hist + (size_t)b * kP;
    int* mb = minb + (size_t)b * kP;
    for (int p = threadIdx.x; p < kP; p += 256) { hb[p] = lh[p]; mb[p] = lm[p]; }
}

// ---- kB: column-reduce hist/minb -> cnt/first; zero accum ----
__global__ __launch_bounds__(256)
void kB_red(const int* __restrict__ hist, const int* __restrict__ minb,
            int* __restrict__ cnt, int* __restrict__ first, float* __restrict__ accum) {
    const int p = blockIdx.x * 256 + threadIdx.x;   // 32 blocks
    int s = 0, mn = kM;
    for (int b = 0; b < NB1; ++b) {
        s  += hist[(size_t)b * kP + p];
        mn  = min(mn, minb[(size_t)b * kP + p]);
    }
    cnt[p] = s;
    first[p] = mn;
    if (p < 2) accum[p] = 0.0f;
}

// ---- kC: class-group partial sums via 128KB LDS table ----
// block b = g*NCH + ch; bank-rotated LDS index p*4 + ((c+p)&3)
__global__ __launch_bounds__(256)
void kC_sum(const unsigned short* __restrict__ pv, const float* __restrict__ pred,
            float* __restrict__ partial) {
    __shared__ float lacc[kP * CPG];   // 131072 B
    const int b = blockIdx.x;
    const int g = b / NCH, ch = b % NCH;
    for (int q = threadIdx.x; q < kP * CPG; q += 256) lacc[q] = 0.0f;
    __syncthreads();

    const int base = ch * CH2;
    const int npix = min(CH2, kM - base);
    const int cls0 = g * CPG;

#pragma unroll 2
    for (int j = threadIdx.x * 2; j < npix; j += 512) {
        const int i = base + j;                       // even
        const unsigned pr = *reinterpret_cast<const unsigned*>(pv + i);
        const int n = i >> 18, hw = i & (kHW - 1);    // pair stays in-plane (i even)
        const float* pp = pred + ((size_t)(n * kC + cls0) << 18) + hw;
        const float2 v0 = *reinterpret_cast<const float2*>(pp);
        const float2 v1 = *reinterpret_cast<const float2*>(pp + kHW);
        const float2 v2 = *reinterpret_cast<const float2*>(pp + 2 * kHW);
        const float2 v3 = *reinterpret_cast<const float2*>(pp + 3 * kHW);
        const unsigned p0 = pr & 0xFFFFu, p1 = pr >> 16;
        if (p0 < kP) {
            const int bse = p0 * 4;
            atomicAdd(&lacc[bse + ((0 + p0) & 3)], v0.x);
            atomicAdd(&lacc[bse + ((1 + p0) & 3)], v1.x);
            atomicAdd(&lacc[bse + ((2 + p0) & 3)], v2.x);
            atomicAdd(&lacc[bse + ((3 + p0) & 3)], v3.x);
        }
        if (j + 1 < npix && p1 < kP) {
            const int bse = p1 * 4;
            atomicAdd(&lacc[bse + ((0 + p1) & 3)], v0.y);
            atomicAdd(&lacc[bse + ((1 + p1) & 3)], v1.y);
            atomicAdd(&lacc[bse + ((2 + p1) & 3)], v2.y);
            atomicAdd(&lacc[bse + ((3 + p1) & 3)], v3.y);
        }
    }
    __syncthreads();

    float* dst = partial + (size_t)b * (kP * CPG);
    for (int q = threadIdx.x; q < kP * CPG; q += 256) {
        const int p = q >> 2, s = q & 3;
        const int c = (s - p) & 3;                    // un-rotate
        dst[(p << 2) + c] = lacc[q];
    }
}

// ---- kD: wave-per-parcel reduce of 51 partials x 20 classes + fused NLL ----
__global__ __launch_bounds__(256)
void kD_loss(const float* __restrict__ partial, const int* __restrict__ cnt,
             const int* __restrict__ first, const int* __restrict__ target,
             const int* __restrict__ cls_num, float* __restrict__ accum) {
    const int wid = threadIdx.x >> 6, lane = threadIdx.x & 63;
    const int p = blockIdx.x * 4 + wid;               // 2048 blocks
    float acc[kC];
#pragma unroll
    for (int c = 0; c < kC; ++c) acc[c] = 0.0f;
    if (lane < NCH) {
#pragma unroll
        for (int g = 0; g < NG; ++g) {
            const float4 f = *reinterpret_cast<const float4*>(
                partial + (((size_t)(g * NCH + lane) * kP + p) << 2));
            acc[g * 4 + 0] += f.x; acc[g * 4 + 1] += f.y;
            acc[g * 4 + 2] += f.z; acc[g * 4 + 3] += f.w;
        }
    }
#pragma unroll
    for (int c = 0; c < kC; ++c) {
        float v = acc[c];
#pragma unroll
        for (int o = 32; o > 0; o >>= 1) v += __shfl_xor(v, o);
        acc[c] = v;
    }
    if (lane == 0) {
        const int n = cnt[p];
        if (n > 0) {
            int f = first[p]; if (f > kM - 1) f = kM - 1;
            const int label = target[f];
            const float inv = 1.0f / (float)n;
            float bal[kC]; float m = -3.402823466e38f;
#pragma unroll
            for (int c = 0; c < kC; ++c) {
                bal[c] = acc[c] * inv + logf((float)cls_num[c]);
                m = fmaxf(m, bal[c]);
            }
            float s = 0.0f;
#pragma unroll
            for (int c = 0; c < kC; ++c) s += expf(bal[c] - m);
            const float lse = m + logf(s);
            float nll = 0.0f;
            if (label >= 0 && label < kC) nll = lse - bal[label];
            atomicAdd(&accum[0], nll);
            atomicAdd(&accum[1], 1.0f);
        }
    }
}

__global__ void kE_out(const float* __restrict__ accum, float* __restrict__ out) {
    out[0] = accum[0] / fmaxf(accum[1], 1.0f);
}

// ---- atomic fallback (proven round-2 path; only if ws is tiny) ----
__global__ __launch_bounds__(256)
void fb_init(float* seg, float* cnt, int* first, float* accum) {
    const int i = blockIdx.x * blockDim.x + threadIdx.x;
    if (i < kP * kC) seg[i] = 0.0f;
    if (i < kP) { cnt[i] = 0.0f; first[i] = kM; }
    if (i < 2) accum[i] = 0.0f;
}
__global__ __launch_bounds__(256)
void fb_scatter(const float* __restrict__ pred, const int* __restrict__ target,
                const int* __restrict__ parcel, float* seg, float* cnt, int* first) {
    const int stride = gridDim.x * blockDim.x;
    for (int idx = blockIdx.x * blockDim.x + threadIdx.x; idx < kM; idx += stride) {
        const int t = target[idx];
        if (t == kIgnore) continue;
        const int p = parcel[idx];
        const int n = idx >> 18, hw = idx & (kHW - 1);
        const float* base = pred + (size_t)n * kC * kHW + hw;
        float* srow = seg + p * kC;
#pragma unroll
        for (int c = 0; c < kC; ++c) atomicAdd(&srow[c], base[(size_t)c * kHW]);
        atomicAdd(&cnt[p], 1.0f);
        atomicMin(&first[p], idx);
    }
}
__global__ __launch_bounds__(256)
void fb_finalize(const float* __restrict__ seg, const float* __restrict__ cnt,
                 const int* __restrict__ first, const int* __restrict__ target,
                 const int* __restrict__ cls_num, float* __restrict__ accum) {
    __shared__ float logcls[kC];
    if (threadIdx.x < kC) logcls[threadIdx.x] = logf((float)cls_num[threadIdx.x]);
    __syncthreads();
    const int p = blockIdx.x * blockDim.x + threadIdx.x;
    float nll = 0.0f, pres = 0.0f;
    if (p < kP) {
        const float c = cnt[p];
        if (c > 0.0f) {
            int f = first[p]; if (f > kM - 1) f = kM - 1;
            const int label = target[f];
            const float inv = 1.0f / c;
            float bal[kC]; float m = -3.402823466e38f;
#pragma unroll
            for (int k = 0; k < kC; ++k) {
                bal[k] = seg[p * kC + k] * inv + logcls[k];
                m = fmaxf(m, bal[k]);
            }
            float s = 0.0f;
#pragma unroll
            for (int k = 0; k < kC; ++k) s += expf(bal[k] - m);
            const float lse = m + logf(s);
            pres = 1.0f;
            if (label >= 0 && label < kC) nll = lse - bal[label];
        }
    }
    float a = nll, b = pres;
#pragma unroll
    for (int o = 32; o > 0; o >>= 1) { a += __shfl_down(a, o); b += __shfl_down(b, o); }
    __shared__ float wsum[4], wcnt[4];
    const int lane = threadIdx.x & 63, wid = threadIdx.x >> 6;
    if (lane == 0) { wsum[wid] = a; wcnt[wid] = b; }
    __syncthreads();
    if (threadIdx.x == 0) {
        float sa = 0.0f, sb = 0.0f;
        for (int w = 0; w < 4; ++w) { sa += wsum[w]; sb += wcnt[w]; }
        atomicAdd(&accum[0], sa);
        atomicAdd(&accum[1], sb);
    }
}

// ---- launch ----
extern "C" void kernel_launch(void* const* d_in, const int* in_sizes, int n_in,
                              void* d_out, int out_size, void* d_ws, size_t ws_size,
                              hipStream_t stream) {
    const float* pred    = (const float*)d_in[0];
    const int*   target  = (const int*)d_in[1];
    const int*   parcel  = (const int*)d_in[2];
    const int*   cls_num = (const int*)d_in[3];
    char* ws = (char*)d_ws;

    if (ws_size >= kNeedMain) {
        unsigned short* pv    = (unsigned short*)(ws + oPv);
        int*   hist    = (int*)(ws + oHist);
        int*   minb    = (int*)(ws + oMinb);
        int*   cnt     = (int*)(ws + oCnt);
        int*   first   = (int*)(ws + oFirst);
        float* accum   = (float*)(ws + oAcc);
        float* partial = (float*)(ws + oPartial);

        kA_pack<<<NB1, 256, 0, stream>>>(target, parcel, pv, hist, minb);
        kB_red<<<kP / 256, 256, 0, stream>>>(hist, minb, cnt, first, accum);
        kC_sum<<<NG * NCH, 256, 0, stream>>>(pv, pred, partial);
        kD_loss<<<kP / 4, 256, 0, stream>>>(partial, cnt, first, target, cls_num, accum);
        kE_out<<<1, 1, 0, stream>>>(accum, (float*)d_out);
    } else {
        float* seg   = (float*)(ws);
        float* cnt   = (float*)(ws + (size_t)kP * kC * 4);
        int*   first = (int*)(ws + (size_t)kP * kC * 4 + (size_t)kP * 4);
        float* accum = (float*)(ws + (size_t)kP * kC * 4 + (size_t)kP * 8);
        fb_init<<<(kP * kC + 255) / 256, 256, 0, stream>>>(seg, cnt, first, accum);
        fb_scatter<<<2048, 256, 0, stream>>>(pred, target, parcel, seg, cnt, first);
        fb_finalize<<<kP / 256, 256, 0, stream>>>(seg, cnt, first, target, cls_num, accum);
        kE_out<<<1, 1, 0, stream>>>(accum, (float*)d_out);
    }
}

// Round 9
// 431.554 us; speedup vs baseline: 1.5093x; 1.5093x over previous
//
#include <hip/hip_runtime.h>
#include <hip/hip_bf16.h>

constexpr int kC  = 20;              // NUM_CLASSES
constexpr int kP  = 8192;            // NUM_PARCELS
constexpr int kIgnore = 255;         // IGNORE_INDEX
constexpr int kHW = 512 * 512;       // 2^18
constexpr int kM  = 8 * kHW;         // 2097152 pixels

constexpr int NB1 = 256;             // kA chunks
constexpr int CH1 = kM / NB1;        // 8192

constexpr int NG  = 5;               // class groups
constexpr int CPG = 4;               // classes per group
constexpr int NCH = 51;              // chunks per group (5*51 = 255 blocks ~ 1/CU)
constexpr int CH2 = (kM + NCH - 1) / NCH;   // 41122 (even)

// ---- workspace layout (bytes) ----
constexpr size_t oPv      = 0;                                    // kM*2 = 4 MB
constexpr size_t oHist    = oPv   + (size_t)kM * 2;               // 8 MB
constexpr size_t oMinb    = oHist + (size_t)NB1 * kP * 4;         // 8 MB
constexpr size_t oCnt     = oMinb + (size_t)NB1 * kP * 4;         // 32 KB
constexpr size_t oFirst   = oCnt  + (size_t)kP * 4;               // 32 KB
constexpr size_t oSeg     = oFirst + (size_t)kP * 4;              // 640 KB
constexpr size_t oAcc     = oSeg  + (size_t)kP * kC * 4;          // 256 B
constexpr size_t oPartial = oAcc + 256;                           // 255*32768*4 = 33.4 MB
constexpr size_t kNeedMain = oPartial + (size_t)NG * NCH * kP * CPG * 4;  // ~54.5 MB

// ---- kA: pack parcel|valid to u16 + per-chunk hist/minb (16 waves/block) ----
__global__ __launch_bounds__(1024)
void kA_pack(const int* __restrict__ target, const int* __restrict__ parcel,
             unsigned short* __restrict__ pv, int* __restrict__ hist,
             int* __restrict__ minb) {
    __shared__ int lh[kP];
    __shared__ int lm[kP];
    const int b = blockIdx.x;
    for (int p = threadIdx.x; p < kP; p += 1024) { lh[p] = 0; lm[p] = kM; }
    __syncthreads();
    const int base = b * CH1;
    for (int j = threadIdx.x; j < CH1; j += 1024) {
        const int i = base + j;
        const int t = target[i];
        const int p = parcel[i];
        const bool valid = (t != kIgnore);
        pv[i] = valid ? (unsigned short)p : (unsigned short)0xFFFF;
        if (valid) { atomicAdd(&lh[p], 1); atomicMin(&lm[p], i); }
    }
    __syncthreads();
    int* hb = hist + (size_t)b * kP;
    int* mb = minb + (size_t)b * kP;
    for (int p = threadIdx.x; p < kP; p += 1024) { hb[p] = lh[p]; mb[p] = lm[p]; }
}

// ---- kB: column-reduce hist/minb -> cnt/first (coalesced); zero accum ----
__global__ __launch_bounds__(256)
void kB_red(const int* __restrict__ hist, const int* __restrict__ minb,
            int* __restrict__ cnt, int* __restrict__ first, float* __restrict__ accum) {
    const int p = blockIdx.x * 256 + threadIdx.x;   // 32 blocks
    int s = 0, mn = kM;
    for (int b = 0; b < NB1; ++b) {
        s  += hist[(size_t)b * kP + p];
        mn  = min(mn, minb[(size_t)b * kP + p]);
    }
    cnt[p] = s;
    first[p] = mn;
    if (p < 2) accum[p] = 0.0f;
}

// ---- kC: class-group partial sums via 128KB LDS table, 16 waves/CU ----
// block b = g*NCH + ch; bank-rotated LDS index p*4 + ((c+p)&3)
__global__ __launch_bounds__(1024)
void kC_sum(const unsigned short* __restrict__ pv, const float* __restrict__ pred,
            float* __restrict__ partial) {
    __shared__ float lacc[kP * CPG];   // 131072 B
    const int b = blockIdx.x;
    const int g = b / NCH, ch = b % NCH;
    for (int q = threadIdx.x; q < kP * CPG; q += 1024) lacc[q] = 0.0f;
    __syncthreads();

    const int base = ch * CH2;
    const int npix = min(CH2, kM - base);
    const int cls0 = g * CPG;

    for (int j = threadIdx.x * 2; j < npix; j += 2048) {
        const int i = base + j;                       // even
        const unsigned pr = *reinterpret_cast<const unsigned*>(pv + i);
        const int n = i >> 18, hw = i & (kHW - 1);    // pair stays in-plane (i even)
        const float* pp = pred + ((size_t)(n * kC + cls0) << 18) + hw;
        const float2 v0 = *reinterpret_cast<const float2*>(pp);
        const float2 v1 = *reinterpret_cast<const float2*>(pp + kHW);
        const float2 v2 = *reinterpret_cast<const float2*>(pp + 2 * kHW);
        const float2 v3 = *reinterpret_cast<const float2*>(pp + 3 * kHW);
        const unsigned p0 = pr & 0xFFFFu, p1 = pr >> 16;
        if (p0 < kP) {
            const int bse = p0 * 4;
            atomicAdd(&lacc[bse + ((0 + p0) & 3)], v0.x);
            atomicAdd(&lacc[bse + ((1 + p0) & 3)], v1.x);
            atomicAdd(&lacc[bse + ((2 + p0) & 3)], v2.x);
            atomicAdd(&lacc[bse + ((3 + p0) & 3)], v3.x);
        }
        if (j + 1 < npix && p1 < kP) {
            const int bse = p1 * 4;
            atomicAdd(&lacc[bse + ((0 + p1) & 3)], v0.y);
            atomicAdd(&lacc[bse + ((1 + p1) & 3)], v1.y);
            atomicAdd(&lacc[bse + ((2 + p1) & 3)], v2.y);
            atomicAdd(&lacc[bse + ((3 + p1) & 3)], v3.y);
        }
    }
    __syncthreads();

    float* dst = partial + (size_t)b * (kP * CPG);
    for (int q = threadIdx.x; q < kP * CPG; q += 1024) {
        const int p = q >> 2, s = q & 3;
        const int c = (s - p) & 3;                    // un-rotate
        dst[(p << 2) + c] = lacc[q];
    }
}

// ---- kD: coalesced column reduce of partials -> seg[p][c] ----
__global__ __launch_bounds__(256)
void kD_sum(const float* __restrict__ partial, float* __restrict__ seg) {
    const int tid = blockIdx.x * 256 + threadIdx.x;   // 163840 = NG*kP*CPG
    const int g = tid / (kP * CPG);
    const int q = tid - g * (kP * CPG);
    float s = 0.0f;
    const float* col = partial + (size_t)g * NCH * (kP * CPG) + q;
    for (int ch = 0; ch < NCH; ++ch)
        s += col[(size_t)ch * (kP * CPG)];            // coalesced across threads
    const int p = q >> 2, c = q & 3;
    seg[(size_t)p * kC + g * CPG + c] = s;
}

// ---- kF: per-parcel balanced-softmax NLL + global mean accumulate ----
__global__ __launch_bounds__(256)
void kF_loss(const float* __restrict__ seg, const int* __restrict__ cnt,
             const int* __restrict__ first, const int* __restrict__ target,
             const int* __restrict__ cls_num, float* __restrict__ accum) {
    __shared__ float logcls[kC];
    if (threadIdx.x < kC) logcls[threadIdx.x] = logf((float)cls_num[threadIdx.x]);
    __syncthreads();
    const int p = blockIdx.x * 256 + threadIdx.x;   // 32 blocks
    float nll = 0.0f, pres = 0.0f;
    const int n = cnt[p];
    if (n > 0) {
        int f = first[p]; if (f > kM - 1) f = kM - 1;
        const int label = target[f];
        const float inv = 1.0f / (float)n;
        float bal[kC]; float m = -3.402823466e38f;
#pragma unroll
        for (int c = 0; c < kC; ++c) {
            bal[c] = seg[(size_t)p * kC + c] * inv + logcls[c];
            m = fmaxf(m, bal[c]);
        }
        float s = 0.0f;
#pragma unroll
        for (int c = 0; c < kC; ++c) s += expf(bal[c] - m);
        const float lse = m + logf(s);
        pres = 1.0f;
        if (label >= 0 && label < kC) nll = lse - bal[label];
    }
    float a = nll, b = pres;
#pragma unroll
    for (int o = 32; o > 0; o >>= 1) { a += __shfl_down(a, o); b += __shfl_down(b, o); }
    __shared__ float wsum[4], wcnt[4];
    const int lane = threadIdx.x & 63, wid = threadIdx.x >> 6;
    if (lane == 0) { wsum[wid] = a; wcnt[wid] = b; }
    __syncthreads();
    if (threadIdx.x == 0) {
        float sa = 0.0f, sb = 0.0f;
        for (int w = 0; w < 4; ++w) { sa += wsum[w]; sb += wcnt[w]; }
        atomicAdd(&accum[0], sa);
        atomicAdd(&accum[1], sb);
    }
}

__global__ void kE_out(const float* __restrict__ accum, float* __restrict__ out) {
    out[0] = accum[0] / fmaxf(accum[1], 1.0f);
}

// ---- atomic fallback (proven round-2 path; only if ws is tiny) ----
__global__ __launch_bounds__(256)
void fb_init(float* seg, float* cnt, int* first, float* accum) {
    const int i = blockIdx.x * blockDim.x + threadIdx.x;
    if (i < kP * kC) seg[i] = 0.0f;
    if (i < kP) { cnt[i] = 0.0f; first[i] = kM; }
    if (i < 2) accum[i] = 0.0f;
}
__global__ __launch_bounds__(256)
void fb_scatter(const float* __restrict__ pred, const int* __restrict__ target,
                const int* __restrict__ parcel, float* seg, float* cnt, int* first) {
    const int stride = gridDim.x * blockDim.x;
    for (int idx = blockIdx.x * blockDim.x + threadIdx.x; idx < kM; idx += stride) {
        const int t = target[idx];
        if (t == kIgnore) continue;
        const int p = parcel[idx];
        const int n = idx >> 18, hw = idx & (kHW - 1);
        const float* base = pred + (size_t)n * kC * kHW + hw;
        float* srow = seg + p * kC;
#pragma unroll
        for (int c = 0; c < kC; ++c) atomicAdd(&srow[c], base[(size_t)c * kHW]);
        atomicAdd(&cnt[p], 1.0f);
        atomicMin(&first[p], idx);
    }
}
__global__ __launch_bounds__(256)
void fb_finalize(const float* __restrict__ seg, const float* __restrict__ cnt,
                 const int* __restrict__ first, const int* __restrict__ target,
                 const int* __restrict__ cls_num, float* __restrict__ accum) {
    __shared__ float logcls[kC];
    if (threadIdx.x < kC) logcls[threadIdx.x] = logf((float)cls_num[threadIdx.x]);
    __syncthreads();
    const int p = blockIdx.x * blockDim.x + threadIdx.x;
    float nll = 0.0f, pres = 0.0f;
    if (p < kP) {
        const float c = cnt[p];
        if (c > 0.0f) {
            int f = first[p]; if (f > kM - 1) f = kM - 1;
            const int label = target[f];
            const float inv = 1.0f / c;
            float bal[kC]; float m = -3.402823466e38f;
#pragma unroll
            for (int k = 0; k < kC; ++k) {
                bal[k] = seg[p * kC + k] * inv + logcls[k];
                m = fmaxf(m, bal[k]);
            }
            float s = 0.0f;
#pragma unroll
            for (int k = 0; k < kC; ++k) s += expf(bal[k] - m);
            const float lse = m + logf(s);
            pres = 1.0f;
            if (label >= 0 && label < kC) nll = lse - bal[label];
        }
    }
    float a = nll, b = pres;
#pragma unroll
    for (int o = 32; o > 0; o >>= 1) { a += __shfl_down(a, o); b += __shfl_down(b, o); }
    __shared__ float wsum[4], wcnt[4];
    const int lane = threadIdx.x & 63, wid = threadIdx.x >> 6;
    if (lane == 0) { wsum[wid] = a; wcnt[wid] = b; }
    __syncthreads();
    if (threadIdx.x == 0) {
        float sa = 0.0f, sb = 0.0f;
        for (int w = 0; w < 4; ++w) { sa += wsum[w]; sb += wcnt[w]; }
        atomicAdd(&accum[0], sa);
        atomicAdd(&accum[1], sb);
    }
}

// ---- launch ----
extern "C" void kernel_launch(void* const* d_in, const int* in_sizes, int n_in,
                              void* d_out, int out_size, void* d_ws, size_t ws_size,
                              hipStream_t stream) {
    const float* pred    = (const float*)d_in[0];
    const int*   target  = (const int*)d_in[1];
    const int*   parcel  = (const int*)d_in[2];
    const int*   cls_num = (const int*)d_in[3];
    char* ws = (char*)d_ws;

    if (ws_size >= kNeedMain) {
        unsigned short* pv = (unsigned short*)(ws + oPv);
        int*   hist    = (int*)(ws + oHist);
        int*   minb    = (int*)(ws + oMinb);
        int*   cnt     = (int*)(ws + oCnt);
        int*   first   = (int*)(ws + oFirst);
        float* seg     = (float*)(ws + oSeg);
        float* accum   = (float*)(ws + oAcc);
        float* partial = (float*)(ws + oPartial);

        kA_pack<<<NB1, 1024, 0, stream>>>(target, parcel, pv, hist, minb);
        kB_red<<<kP / 256, 256, 0, stream>>>(hist, minb, cnt, first, accum);
        kC_sum<<<NG * NCH, 1024, 0, stream>>>(pv, pred, partial);
        kD_sum<<<NG * kP * CPG / 256, 256, 0, stream>>>(partial, seg);
        kF_loss<<<kP / 256, 256, 0, stream>>>(seg, cnt, first, target, cls_num, accum);
        kE_out<<<1, 1, 0, stream>>>(accum, (float*)d_out);
    } else {
        float* seg   = (float*)(ws);
        float* cnt   = (float*)(ws + (size_t)kP * kC * 4);
        int*   first = (int*)(ws + (size_t)kP * kC * 4 + (size_t)kP * 4);
        float* accum = (float*)(ws + (size_t)kP * kC * 4 + (size_t)kP * 8);
        fb_init<<<(kP * kC + 255) / 256, 256, 0, stream>>>(seg, cnt, first, accum);
        fb_scatter<<<2048, 256, 0, stream>>>(pred, target, parcel, seg, cnt, first);
        fb_finalize<<<kP / 256, 256, 0, stream>>>(seg, cnt, first, target, cls_num, accum);
        kE_out<<<1, 1, 0, stream>>>(accum, (float*)d_out);
    }
}